// Round 10
// baseline (196.278 us; speedup 1.0000x reference)
//
#include <hip/hip_runtime.h>

typedef __attribute__((ext_vector_type(8))) short short8;
typedef __attribute__((ext_vector_type(4))) float f32x4;

static __device__ __forceinline__ float bf2f(unsigned short u) {
    unsigned int x = ((unsigned int)u) << 16;
    union { unsigned int i; float f; } c; c.i = x; return c.f;
}
static __device__ __forceinline__ unsigned short f2bf(float f) {
    union { float f; unsigned int i; } c; c.f = f;
    unsigned int x = c.i;
    unsigned int r = (x + 0x7FFFu + ((x >> 16) & 1u)) >> 16;
    return (unsigned short)r;
}
static __device__ __forceinline__ void glds16(const char* g, char* l) {
    __builtin_amdgcn_global_load_lds(
        (const __attribute__((address_space(1))) unsigned int*)g,
        (__attribute__((address_space(3))) unsigned int*)l, 16, 0, 0);
}

// ---------------- prepack W [Cout=128][Cin][7] fp32 -> fragment-linear bf16 ----------------
__global__ void prepack_w(const float* __restrict__ W, unsigned short* __restrict__ Wp,
                          int Cin, int S) {
    int tid = blockIdx.x * blockDim.x + threadIdx.x;
    if (tid >= S * 512) return;
    int lane = tid & 63;
    int f = (tid >> 6) & 7;
    int s = tid >> 9;
    int o = f * 16 + (lane & 15);
    int kbase = s * 32 + 8 * (lane >> 4);
    unsigned short* dst = Wp + (size_t)tid * 8;
#pragma unroll
    for (int j = 0; j < 8; ++j) {
        int kk = kbase + j;
        int t = kk / Cin;
        int c = kk - t * Cin;
        dst[j] = f2bf(W[((size_t)o * Cin + c) * 7 + t]);
    }
}

__global__ void prepack_w_scaled(const float* __restrict__ W, const float2* __restrict__ stats,
                                 unsigned short* __restrict__ Wp, int Cin, int S) {
    int tid = blockIdx.x * blockDim.x + threadIdx.x;
    if (tid >= 2 * S * 512) return;
    int b = tid / (S * 512);
    int rem = tid - b * S * 512;
    int lane = rem & 63;
    int f = (rem >> 6) & 7;
    int s = rem >> 9;
    int o = f * 16 + (lane & 15);
    int kbase = s * 32 + 8 * (lane >> 4);
    unsigned short* dst = Wp + (size_t)tid * 8;
#pragma unroll
    for (int j = 0; j < 8; ++j) {
        int kk = kbase + j;
        int t = kk / Cin;
        int c = kk - t * Cin;
        float scale = stats[b * 128 + c].y;
        dst[j] = f2bf(W[((size_t)o * Cin + c) * 7 + t] * scale);
    }
}

__global__ void fold_bias2(const float* __restrict__ W2, const float* __restrict__ b2,
                           const float2* __restrict__ stats, float* __restrict__ b2out) {
    int b = blockIdx.x, o = threadIdx.x;
    float sum = 0.f;
    for (int c = 0; c < 128; ++c) {
        float2 st = stats[b * 128 + c];
        float sm = st.x * st.y;
        float ws = 0.f;
#pragma unroll
        for (int t = 0; t < 7; ++t) ws += W2[((size_t)o * 128 + c) * 7 + t];
        sum += ws * sm;
    }
    b2out[b * 128 + o] = b2[o] - sum;
}

// ---------------- transpose fp32 [B][C][N] -> bf16 [B][N][ldo] at column offset ----------------
__global__ void transpose_cast(const float* __restrict__ in, unsigned short* __restrict__ out,
                               int C, int N, int ldo, int coff) {
    __shared__ float tile[32][33];
    int b = blockIdx.z;
    int n0 = blockIdx.x * 32;
    int c0 = blockIdx.y * 32;
    const float* inb = in + (size_t)b * C * N;
    unsigned short* outb = out + (size_t)b * N * ldo;
    int tx = threadIdx.x, ty = threadIdx.y;
#pragma unroll
    for (int i = 0; i < 32; i += 8) {
        int c = c0 + ty + i, n = n0 + tx;
        float v = 0.f;
        if (n < N) v = inb[(size_t)c * N + n];
        tile[ty + i][tx] = v;
    }
    __syncthreads();
#pragma unroll
    for (int i = 0; i < 32; i += 8) {
        int n = n0 + ty + i, c = c0 + tx;
        if (n < N) outb[(size_t)n * ldo + coff + c] = f2bf(tile[tx][ty + i]);
    }
}

// ---------------- gather-conv: A LDS-staged, W direct-to-VGPR ----------------
// Block: 128 pts x 128 couts, 4 waves (pg=wid&1: 64-pt half, h=wid>>1: cout half).
// Per k-step/wave: 2 A-glds (8KB A tile per block) + 4 W dwordx4 to regs (3 rotating
// reg buffers, depth-2). A: 4-buf rotation depth-3. Counted vmcnt(6) steady.
// LDS = 32KB -> 2 blocks/CU co-resident; barrier stalls covered by the other block.
template<int CS, int LD, bool STATS>
__global__ __launch_bounds__(256, 2) void conv_gemm(
    const unsigned short* __restrict__ src,
    const int* __restrict__ nbrs,
    const unsigned short* __restrict__ Wp, size_t w_bstride_bytes,
    const float* __restrict__ bias, int bias_bstride,
    unsigned short* __restrict__ dst,
    float2* __restrict__ part,
    int N, int coff)
{
    constexpr int ROWB = CS * 2;
    constexpr int SPT  = CS / 32;   // k-steps per tap
    constexpr int S    = SPT * 7;   // total k-steps

    const int tid  = threadIdx.x;
    const int lane = tid & 63;
    const int wid  = tid >> 6;      // 0..3
    const int pg   = wid & 1;       // point half (compute)
    const int h    = wid >> 1;      // cout half (compute)
    const int l15  = lane & 15;
    const int ks   = lane >> 4;
    const int b    = blockIdx.y;
    const int pblk = blockIdx.x * 128;

    const char* srcb = (const char*)src + (size_t)b * N * ROWB;
    const char* wbc  = (const char*)Wp + (size_t)b * w_bstride_bytes;

    __shared__ char smem[4 * 8192];   // 32KB: 4 A-buffers of 128 rows x 64B

    // --- prologue: wave wid stages rows [wid*32, wid*32+32) ---
    int roffA[14];
    {
        int p = pblk + wid * 32 + (lane & 31);
        int pe = p < N ? p : N - 1;
        int offs[7];
        offs[0] = pe * ROWB;
        const int* nb = nbrs + ((size_t)b * N + pe) * 6;
#pragma unroll
        for (int t = 1; t < 7; ++t) offs[t] = nb[t - 1] * ROWB;
#pragma unroll
        for (int t = 0; t < 7; ++t)
#pragma unroll
            for (int i = 0; i < 2; ++i)
                roffA[t * 2 + i] = __shfl(offs[t], i * 16 + (lane >> 2));
    }
    asm volatile("s_waitcnt vmcnt(0)" ::: "memory");
    __builtin_amdgcn_sched_barrier(0);

    // source-side XOR swizzle (granule permutation within each 64B row)
    const int asw = (((lane & 3) ^ ((lane >> 2) & 3) ^ ((lane >> 4) & 3)) << 4);

    auto stageA = [&](int sidx, int buf) {
        int t = sidx / SPT, kk = sidx % SPT;
        char* base = smem + buf * 8192;
#pragma unroll
        for (int i = 0; i < 2; ++i)
            glds16(srcb + roffA[t * 2 + i] + kk * 64 + asw,
                   base + (wid * 2 + i) * 1024);
    };
    auto loadW = [&](int sidx, short8 w[4]) {
        const short8* gw = (const short8*)(wbc + (size_t)sidx * 8192 + h * 4096) + lane;
#pragma unroll
        for (int fi = 0; fi < 4; ++fi) w[fi] = gw[fi * 64];
    };

    f32x4 acc[4][4];
#pragma unroll
    for (int rg = 0; rg < 4; ++rg)
#pragma unroll
        for (int fi = 0; fi < 4; ++fi) acc[rg][fi] = (f32x4){0.f, 0.f, 0.f, 0.f};

    short8 w0[4], w1[4], w2[4];
    stageA(0, 0);
    stageA(1, 1);
    loadW(0, w0);
    stageA(2, 2);
    loadW(1, w1);

    const int arsw = (((l15 & 3) ^ ((l15 >> 2) & 3)) << 4);  // read-side granule perm

#pragma unroll
    for (int s = 0; s < S; ++s) {
        if (s + 2 < S)      { asm volatile("s_waitcnt vmcnt(6)" ::: "memory"); }
        else if (s + 1 < S) { asm volatile("s_waitcnt vmcnt(4)" ::: "memory"); }
        else                { asm volatile("s_waitcnt vmcnt(0)" ::: "memory"); }
        __builtin_amdgcn_sched_barrier(0);
        __builtin_amdgcn_s_barrier();
        __builtin_amdgcn_sched_barrier(0);
        if (s + 3 < S) stageA(s + 3, (s + 3) & 3);
        if (s + 2 < S) loadW(s + 2, (s % 3 == 0) ? w2 : (s % 3 == 1) ? w0 : w1);

        const short8* w = (s % 3 == 0) ? w0 : (s % 3 == 1) ? w1 : w2;
        const char* Ab = smem + (s & 3) * 8192;
        short8 a[4];
#pragma unroll
        for (int rg = 0; rg < 4; ++rg)
            a[rg] = *(const short8*)(Ab + (pg * 64 + rg * 16 + l15) * 64 +
                                     ((ks << 4) ^ arsw));
        __builtin_amdgcn_s_setprio(1);
#pragma unroll
        for (int rg = 0; rg < 4; ++rg)
#pragma unroll
            for (int fi = 0; fi < 4; ++fi)
                acc[rg][fi] = __builtin_amdgcn_mfma_f32_16x16x32_bf16(
                    a[rg], w[fi], acc[rg][fi], 0, 0, 0);
        __builtin_amdgcn_s_setprio(0);
    }

    // --- epilogue: bias, store bf16, fused stats ---
    const float* biasb = bias + (size_t)b * bias_bstride + h * 64;
    float bias_v[4];
#pragma unroll
    for (int fi = 0; fi < 4; ++fi) bias_v[fi] = biasb[fi * 16 + l15];

    unsigned short* dstb = dst + (size_t)b * N * LD + coff + h * 64;
#pragma unroll
    for (int rg = 0; rg < 4; ++rg) {
#pragma unroll
        for (int r = 0; r < 4; ++r) {
            int p = pblk + pg * 64 + rg * 16 + ks * 4 + r;
            if (p < N) {
#pragma unroll
                for (int fi = 0; fi < 4; ++fi)
                    dstb[(size_t)p * LD + fi * 16 + l15] = f2bf(acc[rg][fi][r] + bias_v[fi]);
            }
        }
    }

    if constexpr (STATS) {
        float s4[4], q4[4];
#pragma unroll
        for (int fi = 0; fi < 4; ++fi) { s4[fi] = 0.f; q4[fi] = 0.f; }
#pragma unroll
        for (int rg = 0; rg < 4; ++rg) {
#pragma unroll
            for (int r = 0; r < 4; ++r) {
                int p = pblk + pg * 64 + rg * 16 + ks * 4 + r;
                if (p < N) {
#pragma unroll
                    for (int fi = 0; fi < 4; ++fi) {
                        float v = acc[rg][fi][r] + bias_v[fi];
                        s4[fi] += v; q4[fi] += v * v;
                    }
                }
            }
        }
#pragma unroll
        for (int fi = 0; fi < 4; ++fi) {
            s4[fi] += __shfl_xor(s4[fi], 16); s4[fi] += __shfl_xor(s4[fi], 32);
            q4[fi] += __shfl_xor(q4[fi], 16); q4[fi] += __shfl_xor(q4[fi], 32);
        }
        __syncthreads();
        float* shs = (float*)smem;       // [4][64]
        float* shq = shs + 256;
        if (lane < 16) {
#pragma unroll
            for (int fi = 0; fi < 4; ++fi) {
                shs[wid * 64 + fi * 16 + l15] = s4[fi];
                shq[wid * 64 + fi * 16 + l15] = q4[fi];
            }
        }
        __syncthreads();
        if (tid < 128) {
            int c = tid;
            int hh = c >> 6, cl = c & 63;   // waves 2*hh (pg0) and 2*hh+1 (pg1)
            float ss = shs[(2 * hh) * 64 + cl] + shs[(2 * hh + 1) * 64 + cl];
            float qq = shq[(2 * hh) * 64 + cl] + shq[(2 * hh + 1) * 64 + cl];
            part[((size_t)b * gridDim.x + blockIdx.x) * 128 + c] = make_float2(ss, qq);
        }
    }
}

// ---------------- final reduce of per-block partials -> (mu, rstd) ----------------
__global__ void stats_final(const float2* __restrict__ part, float2* __restrict__ stats,
                            int N, int NB) {
    int b = blockIdx.x;
    int c = threadIdx.x & 127;
    int r = threadIdx.x >> 7;  // 0..7
    float s = 0.f, sq = 0.f;
    const float2* p = part + (size_t)b * NB * 128 + c;
#pragma unroll 4
    for (int i = r; i < NB; i += 8) {
        float2 v = p[(size_t)i * 128];
        s += v.x; sq += v.y;
    }
    __shared__ float shs[8][128], shq[8][128];
    shs[r][c] = s; shq[r][c] = sq;
    __syncthreads();
    if (r == 0) {
#pragma unroll
        for (int i = 1; i < 8; ++i) { s += shs[i][c]; sq += shq[i][c]; }
        float mu = s / N;
        float var = sq / N - mu * mu;
        stats[b * 128 + c] = make_float2(mu, rsqrtf(var + 1e-5f));
    }
}

// ---------------- final: out[b][o][n] = (z-mu2)*rstd2 + (x1-mu1)*rstd1, fp32 transposed ----------------
__global__ void final_k(const unsigned short* __restrict__ z, const unsigned short* __restrict__ x1,
                        const float2* __restrict__ stats1, const float2* __restrict__ stats2,
                        float* __restrict__ out, int N) {
    __shared__ float tile[32][33];
    int b = blockIdx.z;
    int n0 = blockIdx.x * 32, o0 = blockIdx.y * 32;
    int tx = threadIdx.x, ty = threadIdx.y;
    const unsigned short* zb = z  + (size_t)b * N * 128;
    const unsigned short* xb = x1 + (size_t)b * N * 128;
    float2 st1 = stats1[b * 128 + o0 + tx];
    float2 st2 = stats2[b * 128 + o0 + tx];
#pragma unroll
    for (int i = 0; i < 32; i += 8) {
        int n = n0 + ty + i;
        float v = 0.f;
        if (n < N) {
            float zv = bf2f(zb[(size_t)n * 128 + o0 + tx]);
            float xv = bf2f(xb[(size_t)n * 128 + o0 + tx]);
            v = (zv - st2.x) * st2.y + (xv - st1.x) * st1.y;
        }
        tile[ty + i][tx] = v;
    }
    __syncthreads();
    float* ob = out + (size_t)b * 128 * N;
#pragma unroll
    for (int i = 0; i < 32; i += 8) {
        int o = o0 + ty + i, n = n0 + tx;
        if (n < N) ob[(size_t)o * N + n] = tile[tx][ty + i];
    }
}

extern "C" void kernel_launch(void* const* d_in, const int* in_sizes, int n_in,
                              void* d_out, int out_size, void* d_ws, size_t ws_size,
                              hipStream_t stream) {
    const float* from_up   = (const float*)d_in[0];  // [2,256,30000]
    const float* from_down = (const float*)d_in[1];  // [2,128,30000]
    const int*   neighbors = (const int*)d_in[2];    // [2,30000,6]
    const float* W_up = (const float*)d_in[3];
    const float* b_up = (const float*)d_in[4];
    const float* W_1  = (const float*)d_in[5];
    const float* b_1  = (const float*)d_in[6];
    const float* W_2  = (const float*)d_in[7];
    const float* b_2  = (const float*)d_in[8];
    float* out = (float*)d_out;

    const int B = 2, N = 30000;
    const int S1 = 56, S3 = 28;        // K-steps: 1792/32, 896/32
    const int NBLK = (N + 127) / 128;  // 235 conv blocks per batch

    char* ws = (char*)d_ws;
    size_t off = 0;
    auto alloc = [&](size_t bytes) {
        char* p = ws + off;
        off += (bytes + 255) & ~(size_t)255;
        return p;
    };
    unsigned short* upT   = (unsigned short*)alloc((size_t)B * N * 256 * 2);
    unsigned short* catT  = (unsigned short*)alloc((size_t)B * N * 256 * 2);
    unsigned short* x1    = (unsigned short*)alloc((size_t)B * N * 128 * 2);
    unsigned short* Wp0   = (unsigned short*)alloc((size_t)S1 * 512 * 8 * 2);
    unsigned short* Wp1   = (unsigned short*)alloc((size_t)S1 * 512 * 8 * 2);
    unsigned short* Wp2b  = (unsigned short*)alloc((size_t)B * S3 * 512 * 8 * 2);
    float*  b2fold = (float*)alloc((size_t)B * 128 * 4);
    float2* part   = (float2*)alloc((size_t)B * NBLK * 128 * 8);
    float2* stats1 = (float2*)alloc((size_t)B * 128 * 8);
    float2* stats2 = (float2*)alloc((size_t)B * 128 * 8);
    unsigned short* zbuf = upT;  // reuse (upT dead after conv1)

    // prepack static weights
    prepack_w<<<(S1 * 512 + 255) / 256, 256, 0, stream>>>(W_up, Wp0, 256, S1);
    prepack_w<<<(S1 * 512 + 255) / 256, 256, 0, stream>>>(W_1,  Wp1, 256, S1);

    // transpose inputs to [B][N][C] bf16
    dim3 tb(32, 8);
    transpose_cast<<<dim3((N + 31) / 32, 256 / 32, B), tb, 0, stream>>>(from_up, upT, 256, N, 256, 0);
    transpose_cast<<<dim3((N + 31) / 32, 128 / 32, B), tb, 0, stream>>>(from_down, catT, 128, N, 256, 128);

    dim3 cgrid(NBLK, B);
    // conv1: upT (Cin=256) -> catT[:, 0:128]
    conv_gemm<256, 256, false><<<cgrid, 256, 0, stream>>>(
        upT, neighbors, Wp0, 0, b_up, 0, catT, nullptr, N, 0);
    // conv2: catT (Cin=256) -> x1, fused stats partials
    conv_gemm<256, 128, true><<<cgrid, 256, 0, stream>>>(
        catT, neighbors, Wp1, 0, b_1, 0, x1, part, N, 0);
    stats_final<<<B, 1024, 0, stream>>>((const float2*)part, stats1, N, NBLK);

    // fold norm1 into conv3's weights/bias (per batch)
    prepack_w_scaled<<<(B * S3 * 512 + 255) / 256, 256, 0, stream>>>(W_2, stats1, Wp2b, 128, S3);
    fold_bias2<<<B, 128, 0, stream>>>(W_2, b_2, stats1, b2fold);

    // conv3: x1 (Cin=128, scaled weights) -> zbuf, fused stats partials
    conv_gemm<128, 128, true><<<cgrid, 256, 0, stream>>>(
        x1, neighbors, Wp2b, (size_t)S3 * 8192, b2fold, 128, zbuf, part, N, 0);
    stats_final<<<B, 1024, 0, stream>>>((const float2*)part, stats2, N, NBLK);

    // final: normalize z, add recomputed x1n, transpose to [B][128][N] fp32
    final_k<<<dim3((N + 31) / 32, 4, B), tb, 0, stream>>>(zbuf, x1, stats1, stats2, out, N);
}